// Round 9
// baseline (309.219 us; speedup 1.0000x reference)
//
#include <hip/hip_runtime.h>
#include <hip/hip_bf16.h>
#include <stdint.h>

#define N_NODES 50000
#define N_EDGES 800000
#define IN_FEAT 256
#define OUT_FEAT 256
#define NUM_RELS 64
#define NUM_BASES 8
#define KTOT 2304           // logical K: 8*256 + 256 self-loop
#define KAGG 2048           // A matrix K (bases only)
#define MP 50176            // 784 * 64 padded M
#define NT 36               // K-tiles of 64
#define SCAN_BLKS 196

typedef __attribute__((ext_vector_type(8))) __bf16 bf16x8;
typedef __attribute__((ext_vector_type(4))) __bf16 bf16x4;
typedef __attribute__((ext_vector_type(4))) float f32x4;
typedef __attribute__((ext_vector_type(2))) float f32x2;

static __device__ __forceinline__ void gload_lds16(const void* g, void* l) {
  auto gp = (const __attribute__((address_space(1))) void*)(uintptr_t)g;
  auto lp = (__attribute__((address_space(3))) void*)(uint32_t)(uintptr_t)l;
  __builtin_amdgcn_global_load_lds(gp, lp, 16, 0, 0);
}

// ---------------- x -> bf16 ----------------
__global__ void k_prex(const float* __restrict__ x, __bf16* __restrict__ xb) {
  int i = blockIdx.x * 256 + threadIdx.x;
  const float4* xp = (const float4*)x;
  float4 u = xp[i * 2], v = xp[i * 2 + 1];
  bf16x8 o;
  o[0] = (__bf16)u.x; o[1] = (__bf16)u.y; o[2] = (__bf16)u.z; o[3] = (__bf16)u.w;
  o[4] = (__bf16)v.x; o[5] = (__bf16)v.y; o[6] = (__bf16)v.z; o[7] = (__bf16)v.w;
  *(bf16x8*)(xb + (size_t)i * 8) = o;
}

// ---------------- CSR build ----------------
__global__ void k_count(const int* __restrict__ dst, int* __restrict__ deg) {
  int e = blockIdx.x * 256 + threadIdx.x;
  atomicAdd(&deg[dst[e]], 1);
}

__global__ void k_scan1(const int* __restrict__ deg, int* __restrict__ offs,
                        int* __restrict__ bsum) {
  __shared__ int s[256];
  int t = threadIdx.x;
  int i = blockIdx.x * 256 + t;
  int v = (i < N_NODES) ? deg[i] : 0;
  s[t] = v;
  __syncthreads();
  for (int d = 1; d < 256; d <<= 1) {
    int y = (t >= d) ? s[t - d] : 0;
    __syncthreads();
    s[t] += y;
    __syncthreads();
  }
  if (i < N_NODES) offs[i] = s[t] - v;
  if (t == 255) bsum[blockIdx.x] = s[255];
}

__global__ void k_scan3(int* __restrict__ offs, const int* __restrict__ bsum,
                        int* __restrict__ fill) {
  __shared__ int s[256];
  int t = threadIdx.x;
  s[t] = (t < SCAN_BLKS && t < blockIdx.x) ? bsum[t] : 0;
  __syncthreads();
  for (int d = 128; d; d >>= 1) {
    if (t < d) s[t] += s[t + d];
    __syncthreads();
  }
  int base = s[0];
  int i = blockIdx.x * 256 + t;
  if (i < N_NODES) {
    int o = offs[i] + base;
    offs[i] = o;
    fill[i] = o;
  }
}

__global__ void k_scatter(const int* __restrict__ dst, const int* __restrict__ srcv,
                          const int* __restrict__ ety, const float* __restrict__ norm,
                          int* __restrict__ fill, uint2* __restrict__ erec) {
  int e = blockIdx.x * 256 + threadIdx.x;
  int pos = atomicAdd(&fill[dst[e]], 1);
  erec[pos] = make_uint2((unsigned)srcv[e] | ((unsigned)ety[e] << 16),
                         __float_as_uint(norm[e]));
}

#define AGG_BODY(RX, RY, XV)                                                  \
  do {                                                                        \
    int et_ = (RX) >> 16;                                                     \
    float nm_ = __uint_as_float(RY);                                          \
    f32x2 v0_ = {__uint_as_float((XV).x << 16) * nm_,                         \
                 __uint_as_float((XV).x & 0xffff0000u) * nm_};                 \
    f32x2 v1_ = {__uint_as_float((XV).y << 16) * nm_,                         \
                 __uint_as_float((XV).y & 0xffff0000u) * nm_};                 \
    f32x4 cl_ = *(const f32x4*)&wc[et_ * 8];                                  \
    f32x4 ch_ = *(const f32x4*)&wc[et_ * 8 + 4];                              \
    _Pragma("unroll") for (int b = 0; b < 4; ++b) {                           \
      acc[b][0] += v0_ * cl_[b];                                              \
      acc[b][1] += v1_ * cl_[b];                                              \
      acc[b + 4][0] += v0_ * ch_[b];                                          \
      acc[b + 4][1] += v1_ * ch_[b];                                          \
    }                                                                         \
  } while (0)

// ---------------- per-node aggregation: one wave per node ----------------
__global__ __launch_bounds__(256) void k_agg(
    const __bf16* __restrict__ xb, const float* __restrict__ w_comp,
    const int* __restrict__ offs, const int* __restrict__ fin,
    const uint2* __restrict__ erec, __bf16* __restrict__ A) {
  __shared__ float wc[NUM_RELS * NUM_BASES];
  int t = threadIdx.x;
  wc[t] = w_comp[t];
  wc[t + 256] = w_comp[t + 256];
  __syncthreads();

  int wid = t >> 6, lane = t & 63;
  int node = blockIdx.x * 4 + wid;

  f32x2 acc[NUM_BASES][2];
#pragma unroll
  for (int b = 0; b < NUM_BASES; ++b) {
    acc[b][0] = f32x2{0.f, 0.f};
    acc[b][1] = f32x2{0.f, 0.f};
  }

  int i0 = offs[node];
  int cnt = fin[node] - i0;
  const uint2* rp = erec + i0;
  int lo4 = lane * 4;

  int i = 0;
  for (; i + 8 <= cnt; i += 8) {
    uint2 r[8];
#pragma unroll
    for (int j = 0; j < 8; ++j) r[j] = rp[i + j];
    uint2 xv[8];
#pragma unroll
    for (int j = 0; j < 8; ++j)
      xv[j] = *(const uint2*)(xb + (size_t)(r[j].x & 0xffff) * IN_FEAT + lo4);
#pragma unroll
    for (int j = 0; j < 8; ++j) AGG_BODY(r[j].x, r[j].y, xv[j]);
  }
  for (; i + 4 <= cnt; i += 4) {
    uint2 r[4];
#pragma unroll
    for (int j = 0; j < 4; ++j) r[j] = rp[i + j];
    uint2 xv[4];
#pragma unroll
    for (int j = 0; j < 4; ++j)
      xv[j] = *(const uint2*)(xb + (size_t)(r[j].x & 0xffff) * IN_FEAT + lo4);
#pragma unroll
    for (int j = 0; j < 4; ++j) AGG_BODY(r[j].x, r[j].y, xv[j]);
  }
  for (; i < cnt; ++i) {
    uint2 r = rp[i];
    uint2 xv = *(const uint2*)(xb + (size_t)(r.x & 0xffff) * IN_FEAT + lo4);
    AGG_BODY(r.x, r.y, xv);
  }

  __bf16* Ar = A + (size_t)node * KAGG + lo4;
#pragma unroll
  for (int b = 0; b < NUM_BASES; ++b) {
    bf16x4 o;
    o[0] = (__bf16)acc[b][0][0];
    o[1] = (__bf16)acc[b][0][1];
    o[2] = (__bf16)acc[b][1][0];
    o[3] = (__bf16)acc[b][1][1];
    *(bf16x4*)(Ar + b * 256) = o;
  }
}

// -------- W -> MFMA-fragment order: Wf[F*64 + lane] (16B each), F = kt2*16+nf
// Fragment content: lane holds Wcat[r = kt2*32 + (lane>>4)*8 + j][o = nf*16 + (lane&15)]
// so a wave's B-frag load is ONE coalesced 1KB global read.
__global__ void k_prepwf(const float* __restrict__ weight, const float* __restrict__ loop_w,
                         __bf16* __restrict__ Wf) {
  int tid = blockIdx.x * 256 + threadIdx.x;   // grid 288 -> 73728
  int lane6 = tid & 63;
  int F = tid >> 6;
  int kt2 = F >> 4;
  int nf = F & 15;
  int o = nf * 16 + (lane6 & 15);
  int rbase = kt2 * 32 + (lane6 >> 4) * 8;
  bf16x8 v;
#pragma unroll
  for (int j = 0; j < 8; ++j) {
    int r = rbase + j;
    float f = (r < 2048) ? weight[(size_t)r * 256 + o]
                         : loop_w[(size_t)(r - 2048) * 256 + o];
    v[j] = (__bf16)f;
  }
  *(bf16x8*)(Wf + (size_t)tid * 8) = v;
}

// ---------------- GEMM: out[M][256] = [A | xb] @ Wcat + bias, relu ----------
// BM=64, 4 waves, wave = 64 rows x 64 cols (acc[4][4]).  B comes STRAIGHT from
// L2 into registers via the fragment-packed Wf (no LDS, no barrier dep).
// Only A is LDS-staged: 3 buffers (24KB total -> 3 blocks/CU), stage 2 tiles
// ahead, ONE barrier + one counted vmcnt(2) per K-tile.  Grid 784, balanced.
// A swizzle unchanged: phys chunk = logical ^ (row&7), both sides.
__global__ __launch_bounds__(256, 2) void k_gemm(const __bf16* __restrict__ A,
                                                 const __bf16* __restrict__ xb,
                                                 const __bf16* __restrict__ Wf,
                                                 const float* __restrict__ bias,
                                                 float* __restrict__ out) {
  __shared__ __align__(16) __bf16 sA[3 * 64 * 64];    // 3 x 8KB

  int t = threadIdx.x;
  int wid = t >> 6, lane = t & 63;
  int tm = blockIdx.x;                 // 784 row-tiles of 64
  int rfw = __builtin_amdgcn_readfirstlane(wid);

  f32x4 acc[4][4];
#pragma unroll
  for (int m = 0; m < 4; ++m)
#pragma unroll
    for (int n = 0; n < 4; ++n) acc[m][n] = f32x4{0.f, 0.f, 0.f, 0.f};

  int frow = lane & 15;
  int g = lane >> 4;
  int f7 = frow & 7;
  int kb0 = ((g ^ f7) << 4);
  int kb1 = (((4 + g) ^ f7) << 4);

  // A staging: chunk c = it*256 + t; row = it*32 + (t>>3); phys = t&7
  int rh = t >> 3;
  int qoff = ((t & 7) ^ (rh & 7)) * 8;
  const __bf16* gA[2];
  const __bf16* gX[2];
#pragma unroll
  for (int it = 0; it < 2; ++it) {
    int row = it * 32 + rh;
    gA[it] = A + (size_t)(tm * 64 + row) * KAGG + qoff;
    gX[it] = xb + (size_t)(tm * 64 + row) * IN_FEAT + qoff;
  }
  // wave wid owns cols [wid*64, wid*64+64): frags nf=0..3 at base wid*4
  const __bf16* wfb = Wf + (size_t)(wid * 4) * 512 + lane * 8;

  bf16x8 af[4][2], bcur[4][2];

#define VMWAIT(N) asm volatile("s_waitcnt vmcnt(" #N ")" ::: "memory")
#define BAR()                                       \
  do {                                              \
    asm volatile("" ::: "memory");                  \
    __builtin_amdgcn_s_barrier();                   \
    asm volatile("" ::: "memory");                  \
  } while (0)

#define STAGE(U, BUF)                                                         \
  do {                                                                        \
    char* d_ = (char*)sA + (BUF) * 8192;                                      \
    if ((U) < 32) {                                                           \
      int ko_ = (U) * 64;                                                     \
      gload_lds16(gA[0] + ko_, d_ + rfw * 1024);                              \
      gload_lds16(gA[1] + ko_, d_ + 4096 + rfw * 1024);                       \
    } else {                                                                  \
      int ko_ = ((U) - 32) * 64;                                              \
      gload_lds16(gX[0] + ko_, d_ + rfw * 1024);                              \
      gload_lds16(gX[1] + ko_, d_ + 4096 + rfw * 1024);                       \
    }                                                                         \
  } while (0)

#define LOADB(KT)                                                             \
  do {                                                                        \
    _Pragma("unroll") for (int nf = 0; nf < 4; ++nf) {                        \
      bcur[nf][0] = *(const bf16x8*)(wfb + (size_t)(((KT) * 2 + 0) * 16 + nf) * 512); \
      bcur[nf][1] = *(const bf16x8*)(wfb + (size_t)(((KT) * 2 + 1) * 16 + nf) * 512); \
    }                                                                         \
  } while (0)

#define READ_A(BUF)                                                           \
  do {                                                                        \
    const char* b_ = (const char*)sA + (BUF) * 8192;                          \
    _Pragma("unroll") for (int mf = 0; mf < 4; ++mf) {                        \
      int r_ = mf * 16 + frow;                                                \
      af[mf][0] = *(const bf16x8*)(b_ + r_ * 128 + kb0);                      \
      af[mf][1] = *(const bf16x8*)(b_ + r_ * 128 + kb1);                      \
    }                                                                         \
  } while (0)

#define MFMA32()                                                              \
  do {                                                                        \
    _Pragma("unroll") for (int mf = 0; mf < 4; ++mf)                          \
    _Pragma("unroll") for (int nf = 0; nf < 4; ++nf) {                        \
      acc[mf][nf] = __builtin_amdgcn_mfma_f32_16x16x32_bf16(                  \
          af[mf][0], bcur[nf][0], acc[mf][nf], 0, 0, 0);                      \
      acc[mf][nf] = __builtin_amdgcn_mfma_f32_16x16x32_bf16(                  \
          af[mf][1], bcur[nf][1], acc[mf][nf], 0, 0, 0);                      \
    }                                                                         \
  } while (0)

  // prologue: tile0 -> buf0, tile1 -> buf1; wait tile0 only
  STAGE(0, 0);
  STAGE(1, 1);
  VMWAIT(2);
  BAR();

  for (int kt = 0; kt < NT; ++kt) {
    int cb = kt % 3;
    int nb = (kt + 2) % 3;
    int u2 = (kt + 2 < NT) ? kt + 2 : NT - 1;
    LOADB(kt);                 // 8 coalesced reg loads (L2-hot)
    STAGE(u2, nb);             // 2 gload_lds, 2 tiles ahead
    READ_A(cb);                // 8 ds_read_b128
    __builtin_amdgcn_s_setprio(1);
    MFMA32();                  // 32 MFMA (compiler waits B via its own vmcnt)
    __builtin_amdgcn_s_setprio(0);
    VMWAIT(2);                 // (kt+1)'s A-stages retired; (kt+2)'s may fly
    BAR();                     // publish buf (kt+1)%3; protect ring overwrite
  }
#undef STAGE
#undef LOADB
#undef READ_A
#undef MFMA32
#undef VMWAIT
#undef BAR

  // epilogue: C/D layout col = lane&15, row = (lane>>4)*4 + r
  int r0 = (lane >> 4) * 4;
  int c0 = lane & 15;
#pragma unroll
  for (int m = 0; m < 4; ++m) {
    int rowb = tm * 64 + m * 16 + r0;
#pragma unroll
    for (int n = 0; n < 4; ++n) {
      int col = wid * 64 + n * 16 + c0;
      float bv = bias[col];
#pragma unroll
      for (int r = 0; r < 4; ++r) {
        int row = rowb + r;
        if (row < N_NODES) {
          float v = acc[m][n][r] + bv;
          out[(size_t)row * OUT_FEAT + col] = v > 0.f ? v : 0.f;
        }
      }
    }
  }
}

extern "C" void kernel_launch(void* const* d_in, const int* in_sizes, int n_in,
                              void* d_out, int out_size, void* d_ws, size_t ws_size,
                              hipStream_t stream) {
  const float* x      = (const float*)d_in[0];
  const int*   src    = (const int*)d_in[1];
  const int*   dst    = (const int*)d_in[2];
  const int*   ety    = (const int*)d_in[3];
  const float* norm   = (const float*)d_in[4];
  const float* weight = (const float*)d_in[5];
  const float* w_comp = (const float*)d_in[6];
  const float* h_bias = (const float*)d_in[7];
  const float* loop_w = (const float*)d_in[8];
  float* out = (float*)d_out;

  char* ws = (char*)d_ws;
  __bf16* A  = (__bf16*)ws;                                 // 205.5MB
  size_t off = (size_t)MP * KAGG * 2;
  __bf16* xb = (__bf16*)(ws + off);                         // 25.7MB
  off += (size_t)MP * IN_FEAT * 2;
  __bf16* Wf = (__bf16*)(ws + off);                         // 1.18MB (frag-packed W)
  off += (size_t)256 * KTOT * 2;
  uint2* erec = (uint2*)(ws + off);                         // 6.4MB
  off += (size_t)N_EDGES * 8;
  int* deg   = (int*)(ws + off);
  int* offs  = deg + N_NODES;
  int* fill  = offs + N_NODES;
  int* bsum  = fill + N_NODES;

  hipMemsetAsync(deg, 0, N_NODES * sizeof(int), stream);
  k_prex<<<(N_NODES * IN_FEAT / 8) / 256, 256, 0, stream>>>(x, xb);
  k_count<<<N_EDGES / 256, 256, 0, stream>>>(dst, deg);
  k_scan1<<<SCAN_BLKS, 256, 0, stream>>>(deg, offs, bsum);
  k_scan3<<<SCAN_BLKS, 256, 0, stream>>>(offs, bsum, fill);
  k_scatter<<<N_EDGES / 256, 256, 0, stream>>>(dst, src, ety, norm, fill, erec);
  k_agg<<<N_NODES / 4, 256, 0, stream>>>(xb, w_comp, offs, fill, erec, A);
  k_prepwf<<<288, 256, 0, stream>>>(weight, loop_w, Wf);
  k_gemm<<<MP / 64, 256, 0, stream>>>(A, xb, Wf, h_bias, out);
}

// Round 10
// 301.136 us; speedup vs baseline: 1.0268x; 1.0268x over previous
//
#include <hip/hip_runtime.h>
#include <hip/hip_bf16.h>
#include <stdint.h>

#define N_NODES 50000
#define N_EDGES 800000
#define IN_FEAT 256
#define OUT_FEAT 256
#define NUM_RELS 64
#define NUM_BASES 8
#define KTOT 2304           // logical K: 8*256 + 256 self-loop
#define KAGG 2048           // A matrix K (bases only)
#define MP 50176            // 784 * 64 padded M
#define NT 36               // K-tiles of 64
#define SCAN_BLKS 196

typedef __attribute__((ext_vector_type(8))) __bf16 bf16x8;
typedef __attribute__((ext_vector_type(4))) __bf16 bf16x4;
typedef __attribute__((ext_vector_type(4))) float f32x4;
typedef __attribute__((ext_vector_type(2))) float f32x2;

static __device__ __forceinline__ void gload_lds16(const void* g, void* l) {
  auto gp = (const __attribute__((address_space(1))) void*)(uintptr_t)g;
  auto lp = (__attribute__((address_space(3))) void*)(uint32_t)(uintptr_t)l;
  __builtin_amdgcn_global_load_lds(gp, lp, 16, 0, 0);
}

// ---------------- x -> bf16 ----------------
__global__ void k_prex(const float* __restrict__ x, __bf16* __restrict__ xb) {
  int i = blockIdx.x * 256 + threadIdx.x;
  const float4* xp = (const float4*)x;
  float4 u = xp[i * 2], v = xp[i * 2 + 1];
  bf16x8 o;
  o[0] = (__bf16)u.x; o[1] = (__bf16)u.y; o[2] = (__bf16)u.z; o[3] = (__bf16)u.w;
  o[4] = (__bf16)v.x; o[5] = (__bf16)v.y; o[6] = (__bf16)v.z; o[7] = (__bf16)v.w;
  *(bf16x8*)(xb + (size_t)i * 8) = o;
}

// ---------------- CSR build ----------------
__global__ void k_count(const int* __restrict__ dst, int* __restrict__ deg) {
  int e = blockIdx.x * 256 + threadIdx.x;
  atomicAdd(&deg[dst[e]], 1);
}

__global__ void k_scan1(const int* __restrict__ deg, int* __restrict__ offs,
                        int* __restrict__ bsum) {
  __shared__ int s[256];
  int t = threadIdx.x;
  int i = blockIdx.x * 256 + t;
  int v = (i < N_NODES) ? deg[i] : 0;
  s[t] = v;
  __syncthreads();
  for (int d = 1; d < 256; d <<= 1) {
    int y = (t >= d) ? s[t - d] : 0;
    __syncthreads();
    s[t] += y;
    __syncthreads();
  }
  if (i < N_NODES) offs[i] = s[t] - v;
  if (t == 255) bsum[blockIdx.x] = s[255];
}

__global__ void k_scan3(int* __restrict__ offs, const int* __restrict__ bsum,
                        int* __restrict__ fill) {
  __shared__ int s[256];
  int t = threadIdx.x;
  s[t] = (t < SCAN_BLKS && t < blockIdx.x) ? bsum[t] : 0;
  __syncthreads();
  for (int d = 128; d; d >>= 1) {
    if (t < d) s[t] += s[t + d];
    __syncthreads();
  }
  int base = s[0];
  int i = blockIdx.x * 256 + t;
  if (i < N_NODES) {
    int o = offs[i] + base;
    offs[i] = o;
    fill[i] = o;
  }
}

__global__ void k_scatter(const int* __restrict__ dst, const int* __restrict__ srcv,
                          const int* __restrict__ ety, const float* __restrict__ norm,
                          int* __restrict__ fill, uint2* __restrict__ erec) {
  int e = blockIdx.x * 256 + threadIdx.x;
  int pos = atomicAdd(&fill[dst[e]], 1);
  erec[pos] = make_uint2((unsigned)srcv[e] | ((unsigned)ety[e] << 16),
                         __float_as_uint(norm[e]));
}

#define AGG_BODY(RX, RY, XV)                                                  \
  do {                                                                        \
    int et_ = (RX) >> 16;                                                     \
    float nm_ = __uint_as_float(RY);                                          \
    f32x2 v0_ = {__uint_as_float((XV).x << 16) * nm_,                         \
                 __uint_as_float((XV).x & 0xffff0000u) * nm_};                 \
    f32x2 v1_ = {__uint_as_float((XV).y << 16) * nm_,                         \
                 __uint_as_float((XV).y & 0xffff0000u) * nm_};                 \
    f32x4 cl_ = *(const f32x4*)&wc[et_ * 8];                                  \
    f32x4 ch_ = *(const f32x4*)&wc[et_ * 8 + 4];                              \
    _Pragma("unroll") for (int b = 0; b < 4; ++b) {                           \
      acc[b][0] += v0_ * cl_[b];                                              \
      acc[b][1] += v1_ * cl_[b];                                              \
      acc[b + 4][0] += v0_ * ch_[b];                                          \
      acc[b + 4][1] += v1_ * ch_[b];                                          \
    }                                                                         \
  } while (0)

// ---------------- per-node aggregation: one wave per node ----------------
__global__ __launch_bounds__(256) void k_agg(
    const __bf16* __restrict__ xb, const float* __restrict__ w_comp,
    const int* __restrict__ offs, const int* __restrict__ fin,
    const uint2* __restrict__ erec, __bf16* __restrict__ A) {
  __shared__ float wc[NUM_RELS * NUM_BASES];
  int t = threadIdx.x;
  wc[t] = w_comp[t];
  wc[t + 256] = w_comp[t + 256];
  __syncthreads();

  int wid = t >> 6, lane = t & 63;
  int node = blockIdx.x * 4 + wid;

  f32x2 acc[NUM_BASES][2];
#pragma unroll
  for (int b = 0; b < NUM_BASES; ++b) {
    acc[b][0] = f32x2{0.f, 0.f};
    acc[b][1] = f32x2{0.f, 0.f};
  }

  int i0 = offs[node];
  int cnt = fin[node] - i0;
  const uint2* rp = erec + i0;
  int lo4 = lane * 4;

  int i = 0;
  for (; i + 8 <= cnt; i += 8) {
    uint2 r[8];
#pragma unroll
    for (int j = 0; j < 8; ++j) r[j] = rp[i + j];
    uint2 xv[8];
#pragma unroll
    for (int j = 0; j < 8; ++j)
      xv[j] = *(const uint2*)(xb + (size_t)(r[j].x & 0xffff) * IN_FEAT + lo4);
#pragma unroll
    for (int j = 0; j < 8; ++j) AGG_BODY(r[j].x, r[j].y, xv[j]);
  }
  for (; i + 4 <= cnt; i += 4) {
    uint2 r[4];
#pragma unroll
    for (int j = 0; j < 4; ++j) r[j] = rp[i + j];
    uint2 xv[4];
#pragma unroll
    for (int j = 0; j < 4; ++j)
      xv[j] = *(const uint2*)(xb + (size_t)(r[j].x & 0xffff) * IN_FEAT + lo4);
#pragma unroll
    for (int j = 0; j < 4; ++j) AGG_BODY(r[j].x, r[j].y, xv[j]);
  }
  for (; i < cnt; ++i) {
    uint2 r = rp[i];
    uint2 xv = *(const uint2*)(xb + (size_t)(r.x & 0xffff) * IN_FEAT + lo4);
    AGG_BODY(r.x, r.y, xv);
  }

  __bf16* Ar = A + (size_t)node * KAGG + lo4;
#pragma unroll
  for (int b = 0; b < NUM_BASES; ++b) {
    bf16x4 o;
    o[0] = (__bf16)acc[b][0][0];
    o[1] = (__bf16)acc[b][0][1];
    o[2] = (__bf16)acc[b][1][0];
    o[3] = (__bf16)acc[b][1][1];
    *(bf16x4*)(Ar + b * 256) = o;
  }
}

// -------- W -> MFMA-fragment order: Wf[F*64 + lane] (16B each), F = kt2*16+nf
__global__ void k_prepwf(const float* __restrict__ weight, const float* __restrict__ loop_w,
                         __bf16* __restrict__ Wf) {
  int tid = blockIdx.x * 256 + threadIdx.x;   // grid 288 -> 73728
  int lane6 = tid & 63;
  int F = tid >> 6;
  int kt2 = F >> 4;
  int nf = F & 15;
  int o = nf * 16 + (lane6 & 15);
  int rbase = kt2 * 32 + (lane6 >> 4) * 8;
  bf16x8 v;
#pragma unroll
  for (int j = 0; j < 8; ++j) {
    int r = rbase + j;
    float f = (r < 2048) ? weight[(size_t)r * 256 + o]
                         : loop_w[(size_t)(r - 2048) * 256 + o];
    v[j] = (__bf16)f;
  }
  *(bf16x8*)(Wf + (size_t)tid * 8) = v;
}

// ---------------- GEMM: out[M][256] = [A | xb] @ Wcat + bias, relu ----------
// BM=64, 4 waves, wave = 64x64 (acc[4][4]).  B streamed L2->regs via frag-
// packed Wf, SOFTWARE-PIPELINED ONE TILE AHEAD (named B0/B1, x2-unrolled loop)
// so the MFMA's B operand was loaded a full iteration earlier and the
// compiler's auto-wait is vmcnt(10), not a drain.  A: 3-buffer LDS ring,
// staged 2 ahead via gload_lds; one barrier + one vmcnt(10) per K-tile.
__global__ __launch_bounds__(256, 2) void k_gemm(const __bf16* __restrict__ A,
                                                 const __bf16* __restrict__ xb,
                                                 const __bf16* __restrict__ Wf,
                                                 const float* __restrict__ bias,
                                                 float* __restrict__ out) {
  __shared__ __align__(16) __bf16 sA[3 * 64 * 64];    // 3 x 8KB

  int t = threadIdx.x;
  int wid = t >> 6, lane = t & 63;
  int tm = blockIdx.x;                 // 784 row-tiles of 64
  int rfw = __builtin_amdgcn_readfirstlane(wid);

  f32x4 acc[4][4];
#pragma unroll
  for (int m = 0; m < 4; ++m)
#pragma unroll
    for (int n = 0; n < 4; ++n) acc[m][n] = f32x4{0.f, 0.f, 0.f, 0.f};

  int frow = lane & 15;
  int g = lane >> 4;
  int f7 = frow & 7;
  int kb0 = ((g ^ f7) << 4);
  int kb1 = (((4 + g) ^ f7) << 4);

  int rh = t >> 3;
  int qoff = ((t & 7) ^ (rh & 7)) * 8;
  const __bf16* gA[2];
  const __bf16* gX[2];
#pragma unroll
  for (int it = 0; it < 2; ++it) {
    int row = it * 32 + rh;
    gA[it] = A + (size_t)(tm * 64 + row) * KAGG + qoff;
    gX[it] = xb + (size_t)(tm * 64 + row) * IN_FEAT + qoff;
  }
  const __bf16* wfb = Wf + (size_t)(wid * 4) * 512 + lane * 8;

  bf16x8 af[4][2], B0[4][2], B1[4][2];

#define VMWAIT(N) asm volatile("s_waitcnt vmcnt(" #N ")" ::: "memory")
#define BAR()                                       \
  do {                                              \
    asm volatile("" ::: "memory");                  \
    __builtin_amdgcn_s_barrier();                   \
    asm volatile("" ::: "memory");                  \
  } while (0)

#define STAGE(U, BUF)                                                         \
  do {                                                                        \
    char* d_ = (char*)sA + (BUF) * 8192;                                      \
    if ((U) < 32) {                                                           \
      int ko_ = (U) * 64;                                                     \
      gload_lds16(gA[0] + ko_, d_ + rfw * 1024);                              \
      gload_lds16(gA[1] + ko_, d_ + 4096 + rfw * 1024);                       \
    } else {                                                                  \
      int ko_ = ((U) - 32) * 64;                                              \
      gload_lds16(gX[0] + ko_, d_ + rfw * 1024);                              \
      gload_lds16(gX[1] + ko_, d_ + 4096 + rfw * 1024);                       \
    }                                                                         \
  } while (0)

#define LOADB(KT, DST)                                                        \
  do {                                                                        \
    _Pragma("unroll") for (int nf = 0; nf < 4; ++nf) {                        \
      DST[nf][0] = *(const bf16x8*)(wfb + (size_t)(((KT) * 2 + 0) * 16 + nf) * 512); \
      DST[nf][1] = *(const bf16x8*)(wfb + (size_t)(((KT) * 2 + 1) * 16 + nf) * 512); \
    }                                                                         \
  } while (0)

#define READ_A(BUF)                                                           \
  do {                                                                        \
    const char* b_ = (const char*)sA + (BUF) * 8192;                          \
    _Pragma("unroll") for (int mf = 0; mf < 4; ++mf) {                        \
      int r_ = mf * 16 + frow;                                                \
      af[mf][0] = *(const bf16x8*)(b_ + r_ * 128 + kb0);                      \
      af[mf][1] = *(const bf16x8*)(b_ + r_ * 128 + kb1);                      \
    }                                                                         \
  } while (0)

#define MFMA32(BS)                                                            \
  do {                                                                        \
    _Pragma("unroll") for (int mf = 0; mf < 4; ++mf)                          \
    _Pragma("unroll") for (int nf = 0; nf < 4; ++nf) {                        \
      acc[mf][nf] = __builtin_amdgcn_mfma_f32_16x16x32_bf16(                  \
          af[mf][0], BS[nf][0], acc[mf][nf], 0, 0, 0);                        \
      acc[mf][nf] = __builtin_amdgcn_mfma_f32_16x16x32_bf16(                  \
          af[mf][1], BS[nf][1], acc[mf][nf], 0, 0, 0);                        \
    }                                                                         \
  } while (0)

// one K-tile step: consume BCUR (loaded last step), prefetch BNXT for kt+1
#define STEP(KT, BCUR, BNXT)                                                  \
  do {                                                                        \
    int cb_ = (KT) % 3;                                                       \
    int nb_ = ((KT) + 2) % 3;                                                 \
    int u2_ = ((KT) + 2 < NT) ? (KT) + 2 : NT - 1;                            \
    int un_ = ((KT) + 1 < NT) ? (KT) + 1 : NT - 1;                            \
    LOADB(un_, BNXT);          /* 8 loads: B for kt+1                  */     \
    STAGE(u2_, nb_);           /* 2 gload_lds: A tile kt+2             */     \
    READ_A(cb_);               /* 8 ds_read_b128                       */     \
    __builtin_amdgcn_s_setprio(1);                                            \
    MFMA32(BCUR);              /* compiler waits vmcnt(10)+lgkm        */     \
    __builtin_amdgcn_s_setprio(0);                                            \
    VMWAIT(10);                /* (kt+1)'s A-stage retired; 10 fly     */     \
    BAR();                     /* publish buf (kt+1)%3                 */     \
  } while (0)

  // prologue: B0 <- tile0's B (oldest), then A tiles 0,1
  LOADB(0, B0);
  STAGE(0, 0);
  STAGE(1, 1);
  VMWAIT(2);                   // B0 + tile0 stage retired; tile1 may fly
  BAR();

  for (int kt = 0; kt < NT; kt += 2) {
    STEP(kt, B0, B1);
    STEP(kt + 1, B1, B0);
  }
#undef STEP
#undef STAGE
#undef LOADB
#undef READ_A
#undef MFMA32
#undef VMWAIT
#undef BAR

  // epilogue: C/D layout col = lane&15, row = (lane>>4)*4 + r
  int r0 = (lane >> 4) * 4;
  int c0 = lane & 15;
#pragma unroll
  for (int m = 0; m < 4; ++m) {
    int rowb = tm * 64 + m * 16 + r0;
#pragma unroll
    for (int n = 0; n < 4; ++n) {
      int col = wid * 64 + n * 16 + c0;
      float bv = bias[col];
#pragma unroll
      for (int r = 0; r < 4; ++r) {
        int row = rowb + r;
        if (row < N_NODES) {
          float v = acc[m][n][r] + bv;
          out[(size_t)row * OUT_FEAT + col] = v > 0.f ? v : 0.f;
        }
      }
    }
  }
}

extern "C" void kernel_launch(void* const* d_in, const int* in_sizes, int n_in,
                              void* d_out, int out_size, void* d_ws, size_t ws_size,
                              hipStream_t stream) {
  const float* x      = (const float*)d_in[0];
  const int*   src    = (const int*)d_in[1];
  const int*   dst    = (const int*)d_in[2];
  const int*   ety    = (const int*)d_in[3];
  const float* norm   = (const float*)d_in[4];
  const float* weight = (const float*)d_in[5];
  const float* w_comp = (const float*)d_in[6];
  const float* h_bias = (const float*)d_in[7];
  const float* loop_w = (const float*)d_in[8];
  float* out = (float*)d_out;

  char* ws = (char*)d_ws;
  __bf16* A  = (__bf16*)ws;                                 // 205.5MB
  size_t off = (size_t)MP * KAGG * 2;
  __bf16* xb = (__bf16*)(ws + off);                         // 25.7MB
  off += (size_t)MP * IN_FEAT * 2;
  __bf16* Wf = (__bf16*)(ws + off);                         // 1.18MB (frag-packed W)
  off += (size_t)256 * KTOT * 2;
  uint2* erec = (uint2*)(ws + off);                         // 6.4MB
  off += (size_t)N_EDGES * 8;
  int* deg   = (int*)(ws + off);
  int* offs  = deg + N_NODES;
  int* fill  = offs + N_NODES;
  int* bsum  = fill + N_NODES;

  hipMemsetAsync(deg, 0, N_NODES * sizeof(int), stream);
  k_prex<<<(N_NODES * IN_FEAT / 8) / 256, 256, 0, stream>>>(x, xb);
  k_count<<<N_EDGES / 256, 256, 0, stream>>>(dst, deg);
  k_scan1<<<SCAN_BLKS, 256, 0, stream>>>(deg, offs, bsum);
  k_scan3<<<SCAN_BLKS, 256, 0, stream>>>(offs, bsum, fill);
  k_scatter<<<N_EDGES / 256, 256, 0, stream>>>(dst, src, ety, norm, fill, erec);
  k_agg<<<N_NODES / 4, 256, 0, stream>>>(xb, w_comp, offs, fill, erec, A);
  k_prepwf<<<288, 256, 0, stream>>>(weight, loop_w, Wf);
  k_gemm<<<MP / 64, 256, 0, stream>>>(A, xb, Wf, h_bias, out);
}

// Round 11
// 299.890 us; speedup vs baseline: 1.0311x; 1.0042x over previous
//
#include <hip/hip_runtime.h>
#include <hip/hip_bf16.h>
#include <stdint.h>

#define N_NODES 50000
#define N_EDGES 800000
#define IN_FEAT 256
#define OUT_FEAT 256
#define NUM_RELS 64
#define NUM_BASES 8
#define KTOT 2304           // logical K: 8*256 + 256 self-loop
#define KAGG 2048           // A matrix K (bases only)
#define MP 50176            // 784 * 64 padded M
#define NT 36               // K-tiles of 64
#define SCAN_BLKS 196

typedef __attribute__((ext_vector_type(8))) __bf16 bf16x8;
typedef __attribute__((ext_vector_type(4))) __bf16 bf16x4;
typedef __attribute__((ext_vector_type(4))) float f32x4;
typedef __attribute__((ext_vector_type(2))) float f32x2;

static __device__ __forceinline__ void gload_lds16(const void* g, void* l) {
  auto gp = (const __attribute__((address_space(1))) void*)(uintptr_t)g;
  auto lp = (__attribute__((address_space(3))) void*)(uint32_t)(uintptr_t)l;
  __builtin_amdgcn_global_load_lds(gp, lp, 16, 0, 0);
}

// ---------------- x -> bf16 ----------------
__global__ void k_prex(const float* __restrict__ x, __bf16* __restrict__ xb) {
  int i = blockIdx.x * 256 + threadIdx.x;
  const float4* xp = (const float4*)x;
  float4 u = xp[i * 2], v = xp[i * 2 + 1];
  bf16x8 o;
  o[0] = (__bf16)u.x; o[1] = (__bf16)u.y; o[2] = (__bf16)u.z; o[3] = (__bf16)u.w;
  o[4] = (__bf16)v.x; o[5] = (__bf16)v.y; o[6] = (__bf16)v.z; o[7] = (__bf16)v.w;
  *(bf16x8*)(xb + (size_t)i * 8) = o;
}

// ---------------- CSR build ----------------
__global__ void k_count(const int* __restrict__ dst, int* __restrict__ deg) {
  int e = blockIdx.x * 256 + threadIdx.x;
  atomicAdd(&deg[dst[e]], 1);
}

__global__ void k_scan1(const int* __restrict__ deg, int* __restrict__ offs,
                        int* __restrict__ bsum) {
  __shared__ int s[256];
  int t = threadIdx.x;
  int i = blockIdx.x * 256 + t;
  int v = (i < N_NODES) ? deg[i] : 0;
  s[t] = v;
  __syncthreads();
  for (int d = 1; d < 256; d <<= 1) {
    int y = (t >= d) ? s[t - d] : 0;
    __syncthreads();
    s[t] += y;
    __syncthreads();
  }
  if (i < N_NODES) offs[i] = s[t] - v;
  if (t == 255) bsum[blockIdx.x] = s[255];
}

__global__ void k_scan3(int* __restrict__ offs, const int* __restrict__ bsum,
                        int* __restrict__ fill) {
  __shared__ int s[256];
  int t = threadIdx.x;
  s[t] = (t < SCAN_BLKS && t < blockIdx.x) ? bsum[t] : 0;
  __syncthreads();
  for (int d = 128; d; d >>= 1) {
    if (t < d) s[t] += s[t + d];
    __syncthreads();
  }
  int base = s[0];
  int i = blockIdx.x * 256 + t;
  if (i < N_NODES) {
    int o = offs[i] + base;
    offs[i] = o;
    fill[i] = o;
  }
}

__global__ void k_scatter(const int* __restrict__ dst, const int* __restrict__ srcv,
                          const int* __restrict__ ety, const float* __restrict__ norm,
                          int* __restrict__ fill, uint2* __restrict__ erec) {
  int e = blockIdx.x * 256 + threadIdx.x;
  int pos = atomicAdd(&fill[dst[e]], 1);
  erec[pos] = make_uint2((unsigned)srcv[e] | ((unsigned)ety[e] << 16),
                         __float_as_uint(norm[e]));
}

// ---- per-edge FMA body: et forced to SGPR -> coef reads become s_load ----
#define AGGE(R, XV, ACC)                                                      \
  do {                                                                        \
    int et_ = __builtin_amdgcn_readfirstlane((int)((R).x >> 16));             \
    float nm_ = __uint_as_float((R).y);                                       \
    f32x2 v0_ = {__uint_as_float((XV).x << 16) * nm_,                         \
                 __uint_as_float((XV).x & 0xffff0000u) * nm_};                 \
    f32x2 v1_ = {__uint_as_float((XV).y << 16) * nm_,                         \
                 __uint_as_float((XV).y & 0xffff0000u) * nm_};                 \
    f32x4 cl_ = *(const f32x4*)(w_comp + et_ * 8);                            \
    f32x4 ch_ = *(const f32x4*)(w_comp + et_ * 8 + 4);                        \
    _Pragma("unroll") for (int b = 0; b < 4; ++b) {                           \
      ACC[b][0] += v0_ * cl_[b];                                              \
      ACC[b][1] += v1_ * cl_[b];                                              \
      ACC[b + 4][0] += v0_ * ch_[b];                                          \
      ACC[b + 4][1] += v1_ * ch_[b];                                          \
    }                                                                         \
  } while (0)

#define EDGE4(RP, I, ACC)                                                     \
  do {                                                                        \
    uint2 r0_ = (RP)[(I) + 0], r1_ = (RP)[(I) + 1];                           \
    uint2 r2_ = (RP)[(I) + 2], r3_ = (RP)[(I) + 3];                           \
    uint2 x0_ = *(const uint2*)(xb + (size_t)(r0_.x & 0xffffu) * IN_FEAT + lo4);\
    uint2 x1_ = *(const uint2*)(xb + (size_t)(r1_.x & 0xffffu) * IN_FEAT + lo4);\
    uint2 x2_ = *(const uint2*)(xb + (size_t)(r2_.x & 0xffffu) * IN_FEAT + lo4);\
    uint2 x3_ = *(const uint2*)(xb + (size_t)(r3_.x & 0xffffu) * IN_FEAT + lo4);\
    AGGE(r0_, x0_, ACC); AGGE(r1_, x1_, ACC);                                 \
    AGGE(r2_, x2_, ACC); AGGE(r3_, x3_, ACC);                                 \
  } while (0)

#define EDGE1(RP, I, ACC)                                                     \
  do {                                                                        \
    uint2 r_ = (RP)[(I)];                                                     \
    uint2 x_ = *(const uint2*)(xb + (size_t)(r_.x & 0xffffu) * IN_FEAT + lo4);\
    AGGE(r_, x_, ACC);                                                        \
  } while (0)

// ---------------- aggregation: TWO nodes per wave (dual chains) -------------
// lane owns 4 consecutive features x 8 bases x 2 nodes (64 f32 acc VGPRs, all
// compile-time indexed).  Trip counts readfirstlane'd -> uniform CF -> the
// coef loads go through the scalar cache; two independent gather chains per
// wave double memory-level parallelism vs 1-node/wave.
__global__ __launch_bounds__(256) void k_agg(
    const __bf16* __restrict__ xb, const float* __restrict__ w_comp,
    const int* __restrict__ offs, const int* __restrict__ fin,
    const uint2* __restrict__ erec, __bf16* __restrict__ A) {
  int t = threadIdx.x;
  int wid = t >> 6, lane = t & 63;
  int na = blockIdx.x * 8 + wid * 2;           // grid 6250 -> 50000 nodes
  int lo4 = lane * 4;

  f32x2 acca[NUM_BASES][2], accb[NUM_BASES][2];
#pragma unroll
  for (int b = 0; b < NUM_BASES; ++b) {
    acca[b][0] = f32x2{0.f, 0.f}; acca[b][1] = f32x2{0.f, 0.f};
    accb[b][0] = f32x2{0.f, 0.f}; accb[b][1] = f32x2{0.f, 0.f};
  }

  int i0a = __builtin_amdgcn_readfirstlane(offs[na]);
  int ca  = __builtin_amdgcn_readfirstlane(fin[na]) - i0a;
  int i0b = __builtin_amdgcn_readfirstlane(offs[na + 1]);
  int cb  = __builtin_amdgcn_readfirstlane(fin[na + 1]) - i0b;
  const uint2* rpa = erec + i0a;
  const uint2* rpb = erec + i0b;

  int ia = 0, ib = 0;
  int mm = (ca < cb ? ca : cb) & ~3;
  for (; ia < mm; ia += 4, ib += 4) {          // dual interleaved chains
    EDGE4(rpa, ia, acca);
    EDGE4(rpb, ib, accb);
  }
  for (; ia + 4 <= ca; ia += 4) EDGE4(rpa, ia, acca);
  for (; ib + 4 <= cb; ib += 4) EDGE4(rpb, ib, accb);
  for (; ia < ca; ++ia) EDGE1(rpa, ia, acca);
  for (; ib < cb; ++ib) EDGE1(rpb, ib, accb);

  __bf16* Ara = A + (size_t)na * KAGG + lo4;
  __bf16* Arb = A + (size_t)(na + 1) * KAGG + lo4;
#pragma unroll
  for (int b = 0; b < NUM_BASES; ++b) {
    bf16x4 oa, ob;
    oa[0] = (__bf16)acca[b][0][0]; oa[1] = (__bf16)acca[b][0][1];
    oa[2] = (__bf16)acca[b][1][0]; oa[3] = (__bf16)acca[b][1][1];
    *(bf16x4*)(Ara + b * 256) = oa;
    ob[0] = (__bf16)accb[b][0][0]; ob[1] = (__bf16)accb[b][0][1];
    ob[2] = (__bf16)accb[b][1][0]; ob[3] = (__bf16)accb[b][1][1];
    *(bf16x4*)(Arb + b * 256) = ob;
  }
}

// -------- W -> MFMA-fragment order: Wf[F*64 + lane] (16B each), F = kt2*16+nf
__global__ void k_prepwf(const float* __restrict__ weight, const float* __restrict__ loop_w,
                         __bf16* __restrict__ Wf) {
  int tid = blockIdx.x * 256 + threadIdx.x;   // grid 288 -> 73728
  int lane6 = tid & 63;
  int F = tid >> 6;
  int kt2 = F >> 4;
  int nf = F & 15;
  int o = nf * 16 + (lane6 & 15);
  int rbase = kt2 * 32 + (lane6 >> 4) * 8;
  bf16x8 v;
#pragma unroll
  for (int j = 0; j < 8; ++j) {
    int r = rbase + j;
    float f = (r < 2048) ? weight[(size_t)r * 256 + o]
                         : loop_w[(size_t)(r - 2048) * 256 + o];
    v[j] = (__bf16)f;
  }
  *(bf16x8*)(Wf + (size_t)tid * 8) = v;
}

// ---------------- GEMM: out[M][256] = [A | xb] @ Wcat + bias, relu ----------
// (byte-identical to round 10 for attribution)
__global__ __launch_bounds__(256, 2) void k_gemm(const __bf16* __restrict__ A,
                                                 const __bf16* __restrict__ xb,
                                                 const __bf16* __restrict__ Wf,
                                                 const float* __restrict__ bias,
                                                 float* __restrict__ out) {
  __shared__ __align__(16) __bf16 sA[3 * 64 * 64];    // 3 x 8KB

  int t = threadIdx.x;
  int wid = t >> 6, lane = t & 63;
  int tm = blockIdx.x;                 // 784 row-tiles of 64
  int rfw = __builtin_amdgcn_readfirstlane(wid);

  f32x4 acc[4][4];
#pragma unroll
  for (int m = 0; m < 4; ++m)
#pragma unroll
    for (int n = 0; n < 4; ++n) acc[m][n] = f32x4{0.f, 0.f, 0.f, 0.f};

  int frow = lane & 15;
  int g = lane >> 4;
  int f7 = frow & 7;
  int kb0 = ((g ^ f7) << 4);
  int kb1 = (((4 + g) ^ f7) << 4);

  int rh = t >> 3;
  int qoff = ((t & 7) ^ (rh & 7)) * 8;
  const __bf16* gA[2];
  const __bf16* gX[2];
#pragma unroll
  for (int it = 0; it < 2; ++it) {
    int row = it * 32 + rh;
    gA[it] = A + (size_t)(tm * 64 + row) * KAGG + qoff;
    gX[it] = xb + (size_t)(tm * 64 + row) * IN_FEAT + qoff;
  }
  const __bf16* wfb = Wf + (size_t)(wid * 4) * 512 + lane * 8;

  bf16x8 af[4][2], B0[4][2], B1[4][2];

#define VMWAIT(N) asm volatile("s_waitcnt vmcnt(" #N ")" ::: "memory")
#define BAR()                                       \
  do {                                              \
    asm volatile("" ::: "memory");                  \
    __builtin_amdgcn_s_barrier();                   \
    asm volatile("" ::: "memory");                  \
  } while (0)

#define STAGE(U, BUF)                                                         \
  do {                                                                        \
    char* d_ = (char*)sA + (BUF) * 8192;                                      \
    if ((U) < 32) {                                                           \
      int ko_ = (U) * 64;                                                     \
      gload_lds16(gA[0] + ko_, d_ + rfw * 1024);                              \
      gload_lds16(gA[1] + ko_, d_ + 4096 + rfw * 1024);                       \
    } else {                                                                  \
      int ko_ = ((U) - 32) * 64;                                              \
      gload_lds16(gX[0] + ko_, d_ + rfw * 1024);                              \
      gload_lds16(gX[1] + ko_, d_ + 4096 + rfw * 1024);                       \
    }                                                                         \
  } while (0)

#define LOADB(KT, DST)                                                        \
  do {                                                                        \
    _Pragma("unroll") for (int nf = 0; nf < 4; ++nf) {                        \
      DST[nf][0] = *(const bf16x8*)(wfb + (size_t)(((KT) * 2 + 0) * 16 + nf) * 512); \
      DST[nf][1] = *(const bf16x8*)(wfb + (size_t)(((KT) * 2 + 1) * 16 + nf) * 512); \
    }                                                                         \
  } while (0)

#define READ_A(BUF)                                                           \
  do {                                                                        \
    const char* b_ = (const char*)sA + (BUF) * 8192;                          \
    _Pragma("unroll") for (int mf = 0; mf < 4; ++mf) {                        \
      int r_ = mf * 16 + frow;                                                \
      af[mf][0] = *(const bf16x8*)(b_ + r_ * 128 + kb0);                      \
      af[mf][1] = *(const bf16x8*)(b_ + r_ * 128 + kb1);                      \
    }                                                                         \
  } while (0)

#define MFMA32(BS)                                                            \
  do {                                                                        \
    _Pragma("unroll") for (int mf = 0; mf < 4; ++mf)                          \
    _Pragma("unroll") for (int nf = 0; nf < 4; ++nf) {                        \
      acc[mf][nf] = __builtin_amdgcn_mfma_f32_16x16x32_bf16(                  \
          af[mf][0], BS[nf][0], acc[mf][nf], 0, 0, 0);                        \
      acc[mf][nf] = __builtin_amdgcn_mfma_f32_16x16x32_bf16(                  \
          af[mf][1], BS[nf][1], acc[mf][nf], 0, 0, 0);                        \
    }                                                                         \
  } while (0)

#define STEP(KT, BCUR, BNXT)                                                  \
  do {                                                                        \
    int cb_ = (KT) % 3;                                                       \
    int nb_ = ((KT) + 2) % 3;                                                 \
    int u2_ = ((KT) + 2 < NT) ? (KT) + 2 : NT - 1;                            \
    int un_ = ((KT) + 1 < NT) ? (KT) + 1 : NT - 1;                            \
    LOADB(un_, BNXT);                                                         \
    STAGE(u2_, nb_);                                                          \
    READ_A(cb_);                                                              \
    __builtin_amdgcn_s_setprio(1);                                            \
    MFMA32(BCUR);                                                             \
    __builtin_amdgcn_s_setprio(0);                                            \
    VMWAIT(10);                                                               \
    BAR();                                                                    \
  } while (0)

  LOADB(0, B0);
  STAGE(0, 0);
  STAGE(1, 1);
  VMWAIT(2);
  BAR();

  for (int kt = 0; kt < NT; kt += 2) {
    STEP(kt, B0, B1);
    STEP(kt + 1, B1, B0);
  }
#undef STEP
#undef STAGE
#undef LOADB
#undef READ_A
#undef MFMA32
#undef VMWAIT
#undef BAR

  int r0 = (lane >> 4) * 4;
  int c0 = lane & 15;
#pragma unroll
  for (int m = 0; m < 4; ++m) {
    int rowb = tm * 64 + m * 16 + r0;
#pragma unroll
    for (int n = 0; n < 4; ++n) {
      int col = wid * 64 + n * 16 + c0;
      float bv = bias[col];
#pragma unroll
      for (int r = 0; r < 4; ++r) {
        int row = rowb + r;
        if (row < N_NODES) {
          float v = acc[m][n][r] + bv;
          out[(size_t)row * OUT_FEAT + col] = v > 0.f ? v : 0.f;
        }
      }
    }
  }
}

extern "C" void kernel_launch(void* const* d_in, const int* in_sizes, int n_in,
                              void* d_out, int out_size, void* d_ws, size_t ws_size,
                              hipStream_t stream) {
  const float* x      = (const float*)d_in[0];
  const int*   src    = (const int*)d_in[1];
  const int*   dst    = (const int*)d_in[2];
  const int*   ety    = (const int*)d_in[3];
  const float* norm   = (const float*)d_in[4];
  const float* weight = (const float*)d_in[5];
  const float* w_comp = (const float*)d_in[6];
  const float* h_bias = (const float*)d_in[7];
  const float* loop_w = (const float*)d_in[8];
  float* out = (float*)d_out;

  char* ws = (char*)d_ws;
  __bf16* A  = (__bf16*)ws;                                 // 205.5MB
  size_t off = (size_t)MP * KAGG * 2;
  __bf16* xb = (__bf16*)(ws + off);                         // 25.7MB
  off += (size_t)MP * IN_FEAT * 2;
  __bf16* Wf = (__bf16*)(ws + off);                         // 1.18MB (frag-packed W)
  off += (size_t)256 * KTOT * 2;
  uint2* erec = (uint2*)(ws + off);                         // 6.4MB
  off += (size_t)N_EDGES * 8;
  int* deg   = (int*)(ws + off);
  int* offs  = deg + N_NODES;
  int* fill  = offs + N_NODES;
  int* bsum  = fill + N_NODES;

  hipMemsetAsync(deg, 0, N_NODES * sizeof(int), stream);
  k_prex<<<(N_NODES * IN_FEAT / 8) / 256, 256, 0, stream>>>(x, xb);
  k_count<<<N_EDGES / 256, 256, 0, stream>>>(dst, deg);
  k_scan1<<<SCAN_BLKS, 256, 0, stream>>>(deg, offs, bsum);
  k_scan3<<<SCAN_BLKS, 256, 0, stream>>>(offs, bsum, fill);
  k_scatter<<<N_EDGES / 256, 256, 0, stream>>>(dst, src, ety, norm, fill, erec);
  k_agg<<<N_NODES / 8, 256, 0, stream>>>(xb, w_comp, offs, fill, erec, A);
  k_prepwf<<<288, 256, 0, stream>>>(weight, loop_w, Wf);
  k_gemm<<<MP / 64, 256, 0, stream>>>(A, xb, Wf, h_bias, out);
}